// Round 2
// baseline (921.392 us; speedup 1.0000x reference)
//
#include <hip/hip_runtime.h>
#include <hip/hip_bf16.h>
#include <math.h>

#define NSEG  1024
#define HID   256      // x feature dim
#define H2    128      // hidden dim
#define TM    32       // rows per tile
#define BLOCK 512      // 8 waves; wave owns 16 H2 cols

typedef __attribute__((ext_vector_type(8))) __bf16 bf16x8;
typedef __attribute__((ext_vector_type(4))) float  f32x4;
typedef unsigned int   uint32;
typedef unsigned short ushort16;

__device__ __forceinline__ bf16x8 pack8(f32x4 lo, f32x4 hi) {
    bf16x8 b;
    b[0] = (__bf16)lo[0]; b[1] = (__bf16)lo[1]; b[2] = (__bf16)lo[2]; b[3] = (__bf16)lo[3];
    b[4] = (__bf16)hi[0]; b[5] = (__bf16)hi[1]; b[6] = (__bf16)hi[2]; b[7] = (__bf16)hi[3];
    return b;
}

// One block per segment (batch sorted). x tiles staged in LDS as bf16,
// XOR-swizzled on 16B units: unit' = unit ^ (row & 7)  -> conflict-free
// ds_read_b128 A-frags AND conflict-free per-element weighted-sum reads.
// Wave w computes h[32 rows][cols w*16..w*16+16) via mfma_f32_16x16x32_bf16.
// Online softmax; thread tid: dim = tid&255, row-half = tid>>8 (combined at end).
__global__ __launch_bounds__(BLOCK, 4)
void attn_pool_kernel(const float* __restrict__ x, const int* __restrict__ batch,
                      const float* __restrict__ W1, const float* __restrict__ b1,
                      const float* __restrict__ W2, float* __restrict__ out, int N)
{
    __shared__ __align__(16) unsigned short xs[2][TM * HID];   // 2 x 16 KB bf16
    __shared__ float s_part[8][TM];
    __shared__ __align__(16) float s_fin[TM];
    __shared__ float acc_hi[HID];
    __shared__ float l_hi;

    const int tid  = threadIdx.x;
    const int wid  = tid >> 6;        // 0..7
    const int lane = tid & 63;
    const int l15  = lane & 15;
    const int lg   = lane >> 4;       // 0..3
    const int s7   = l15 & 7;
    const int seg  = blockIdx.x;

    // segment bounds (batch sorted ascending)
    int lo = 0, hi = N;
    while (lo < hi) { int mid = (lo + hi) >> 1; if (batch[mid] <  seg) lo = mid + 1; else hi = mid; }
    const int start = lo;
    hi = N;
    while (lo < hi) { int mid = (lo + hi) >> 1; if (batch[mid] <= seg) lo = mid + 1; else hi = mid; }
    const int end = lo;

    // ---- W1 B-frags: wave owns cols [wid*16, wid*16+16) -> 32 VGPR ----
    const int col = wid * 16 + l15;
    bf16x8 bfrag[8];
    #pragma unroll
    for (int kt = 0; kt < 8; ++kt) {
        bf16x8 b;
        #pragma unroll
        for (int j = 0; j < 8; ++j) b[j] = (__bf16)W1[(kt * 32 + lg * 8 + j) * H2 + col];
        bfrag[kt] = b;
    }
    const float b1v = b1[col];
    const float w2v = W2[col];

    const int cnt    = end - start;
    const int ntiles = (cnt + TM - 1) / TM;

    // staging geometry: thread handles 16B-units (sr, suc) and (sr+16, suc)
    const int sr  = tid >> 5;          // 0..15
    const int suc = tid & 31;          // unit col (8 floats -> 8 bf16)
    const int so0 = ((sr * 32) + (suc ^ (sr & 7))) * 16;   // swizzled byte offset
    const int so1 = so0 + 16 * 32 * 16;                    // rows +16 (same r&7)

    char* const xs0 = (char*)&xs[0][0];
    f32x4 ld0, ld1, ld2, ld3;

    if (ntiles > 0) {   // prologue: stage tile 0
        const int last = end - 1;
        int gr0 = start + sr;      if (gr0 > last) gr0 = last;
        int gr1 = start + sr + 16; if (gr1 > last) gr1 = last;
        const float* p0 = x + (size_t)gr0 * HID + suc * 8;
        const float* p1 = x + (size_t)gr1 * HID + suc * 8;
        ld0 = *(const f32x4*)p0; ld1 = *(const f32x4*)(p0 + 4);
        ld2 = *(const f32x4*)p1; ld3 = *(const f32x4*)(p1 + 4);
        *(bf16x8*)(xs0 + so0) = pack8(ld0, ld1);
        *(bf16x8*)(xs0 + so1) = pack8(ld2, ld3);
    }
    __syncthreads();

    float m_run = -INFINITY, l_run = 0.f, acc_d = 0.f;
    const int d     = tid & (HID - 1);
    const int du    = d >> 3;
    const int dl    = d & 7;
    const int row_h = (tid >> 8) * 16;   // 0 or 16: this thread's row half

    for (int t = 0; t < ntiles; ++t) {
        const int  cur      = t & 1;
        const int  row0     = start + t * TM;
        const bool has_next = (t + 1) < ntiles;
        const char* xb = xs0 + cur * (TM * HID * 2);
        const unsigned short* xbu = (const unsigned short*)xb;

        // T14: issue next tile's global loads now; LDS write after compute
        if (has_next) {
            const int last = end - 1;
            int gr0 = row0 + TM + sr;      if (gr0 > last) gr0 = last;
            int gr1 = row0 + TM + sr + 16; if (gr1 > last) gr1 = last;
            const float* p0 = x + (size_t)gr0 * HID + suc * 8;
            const float* p1 = x + (size_t)gr1 * HID + suc * 8;
            ld0 = *(const f32x4*)p0; ld1 = *(const f32x4*)(p0 + 4);
            ld2 = *(const f32x4*)p1; ld3 = *(const f32x4*)(p1 + 4);
        }

        // ---- h = x_tile @ W1 (bf16 MFMA) ----
        f32x4 acc0 = {0.f, 0.f, 0.f, 0.f}, acc1 = {0.f, 0.f, 0.f, 0.f};
        const char* arow = xb + l15 * 512;   // row l15 base (512 B/row)
        #pragma unroll
        for (int kt = 0; kt < 8; ++kt) {
            const int sw = (((kt * 4) + lg) ^ s7) * 16;
            bf16x8 a0 = *(const bf16x8*)(arow + sw);           // rows 0..15
            bf16x8 a1 = *(const bf16x8*)(arow + 8192 + sw);    // rows 16..31
            acc0 = __builtin_amdgcn_mfma_f32_16x16x32_bf16(a0, bfrag[kt], acc0, 0, 0, 0);
            acc1 = __builtin_amdgcn_mfma_f32_16x16x32_bf16(a1, bfrag[kt], acc1, 0, 0, 0);
        }

        // ---- partial scores: p = tanh(h + b1) * W2, reduced over 16 cols ----
        // C/D layout: col = l15, row-in-16 = lg*4 + r
        #pragma unroll
        for (int mt = 0; mt < 2; ++mt) {
            #pragma unroll
            for (int r = 0; r < 4; ++r) {
                float h  = (mt ? acc1[r] : acc0[r]) + b1v;
                float e2 = __expf(fminf(2.f * h, 80.f));
                float th = __fdividef(e2 - 1.f, e2 + 1.f);
                float p  = th * w2v;
                p += __shfl_xor(p, 1);
                p += __shfl_xor(p, 2);
                p += __shfl_xor(p, 4);
                p += __shfl_xor(p, 8);
                if (l15 == 0) s_part[wid][mt * 16 + lg * 4 + r] = p;
            }
        }
        __syncthreads();
        if (tid < TM) {
            float s = s_part[0][tid];
            #pragma unroll
            for (int w = 1; w < 8; ++w) s += s_part[w][tid];
            if (row0 + tid >= end) s = -1e30f;   // mask tail rows
            s_fin[tid] = s;
        }
        __syncthreads();

        // ---- online softmax update (vectorized s_fin reads) ----
        float tmax = -1e30f;
        #pragma unroll
        for (int i = 0; i < 8; ++i) {
            f32x4 v = *(const f32x4*)&s_fin[i * 4];
            tmax = fmaxf(tmax, fmaxf(fmaxf(v[0], v[1]), fmaxf(v[2], v[3])));
        }
        const float m_new = fmaxf(m_run, tmax);
        const float scale = __expf(m_run - m_new);   // first tile: exp(-inf)=0
        acc_d *= scale;
        l_run *= scale;

        f32x4 sh0 = *(const f32x4*)&s_fin[row_h + 0];
        f32x4 sh1 = *(const f32x4*)&s_fin[row_h + 4];
        f32x4 sh2 = *(const f32x4*)&s_fin[row_h + 8];
        f32x4 sh3 = *(const f32x4*)&s_fin[row_h + 12];
        #pragma unroll
        for (int q = 0; q < 4; ++q) {
            f32x4 sv = (q == 0) ? sh0 : (q == 1) ? sh1 : (q == 2) ? sh2 : sh3;
            #pragma unroll
            for (int j = 0; j < 4; ++j) {
                const int rr  = q * 4 + j;              // row within half (row&7 = rr&7)
                const float e = __expf(sv[j] - m_new);  // masked rows -> 0
                l_run += e;
                const int idx = (row_h + rr) * HID + ((du ^ (rr & 7)) << 3) + dl;
                const float xv = __uint_as_float(((uint32)xbu[idx]) << 16);
                acc_d = fmaf(e, xv, acc_d);
            }
        }
        m_run = m_new;

        // write staged regs (bf16, swizzled) into the other buffer
        if (has_next) {
            char* xn = xs0 + (cur ^ 1) * (TM * HID * 2);
            *(bf16x8*)(xn + so0) = pack8(ld0, ld1);
            *(bf16x8*)(xn + so1) = pack8(ld2, ld3);
        }
        __syncthreads();
    }

    // combine the two row-halves; empty segment -> 0/(0+1e-8) = 0
    if (tid >= HID) {
        acc_hi[d] = acc_d;
        if (tid == HID) l_hi = l_run;
    }
    __syncthreads();
    if (tid < HID) {
        const float a = acc_d + acc_hi[tid];
        const float l = l_run + l_hi;
        out[seg * HID + tid] = a / (l + 1e-8f);
    }
}

extern "C" void kernel_launch(void* const* d_in, const int* in_sizes, int n_in,
                              void* d_out, int out_size, void* d_ws, size_t ws_size,
                              hipStream_t stream) {
    const float* x     = (const float*)d_in[0];
    const int*   batch = (const int*)d_in[1];
    const float* W1    = (const float*)d_in[2];
    const float* b1    = (const float*)d_in[3];
    const float* W2    = (const float*)d_in[4];
    // d_in[5] = b2: uniform shift, cancels in the segment softmax — unused.
    float* out = (float*)d_out;
    const int N = in_sizes[1];

    attn_pool_kernel<<<NSEG, BLOCK, 0, stream>>>(x, batch, W1, b1, W2, out, N);
}

// Round 3
// 725.350 us; speedup vs baseline: 1.2703x; 1.2703x over previous
//
#include <hip/hip_runtime.h>
#include <hip/hip_bf16.h>
#include <math.h>

#define NSEG  1024
#define HID   256      // x feature dim
#define H2    128      // hidden dim
#define TM    32       // rows per tile
#define BLOCK 512      // 8 waves; wave owns 16 H2 cols

typedef __attribute__((ext_vector_type(8))) __bf16 bf16x8;
typedef __attribute__((ext_vector_type(4))) float  f32x4;
typedef unsigned int uint32;

__device__ __forceinline__ bf16x8 pack8(f32x4 lo, f32x4 hi) {
    bf16x8 b;
    b[0] = (__bf16)lo[0]; b[1] = (__bf16)lo[1]; b[2] = (__bf16)lo[2]; b[3] = (__bf16)lo[3];
    b[4] = (__bf16)hi[0]; b[5] = (__bf16)hi[1]; b[6] = (__bf16)hi[2]; b[7] = (__bf16)hi[3];
    return b;
}

// async 16B global->LDS (no VGPR round-trip, nothing to spill)
__device__ __forceinline__ void gload16(const float* g, const float* l) {
    __builtin_amdgcn_global_load_lds(
        (const __attribute__((address_space(1))) unsigned int*)g,
        (__attribute__((address_space(3))) unsigned int*)l, 16, 0, 0);
}

// raw barriers with hand-placed waits (m201 template): lgkm-only barriers let
// the async tile loads stay in flight across the score-reduce phases.
#define BAR_LGKM() do { asm volatile("s_waitcnt lgkmcnt(0)" ::: "memory"); \
                        __builtin_amdgcn_s_barrier(); } while (0)
#define BAR_ALL()  do { asm volatile("s_waitcnt vmcnt(0) lgkmcnt(0)" ::: "memory"); \
                        __builtin_amdgcn_s_barrier(); } while (0)

// One block per segment (batch sorted). x tiles staged f32 in LDS via
// global_load_lds with PRE-SWIZZLED global source: LDS slot (r,u) holds
// global 16B-unit u^(r&7) of row r (per-wave XOR constant = wid). A-frag
// ds_read_b128s and the per-dim weighted-sum reads are then conflict-free
// (structurally balanced). f32->bf16 pack happens at A-frag read (cvt_pk).
__global__ __launch_bounds__(BLOCK, 2)
void attn_pool_kernel(const float* __restrict__ x, const int* __restrict__ batch,
                      const float* __restrict__ W1, const float* __restrict__ b1,
                      const float* __restrict__ W2, float* __restrict__ out, int N)
{
    __shared__ __align__(16) float xs[2][TM * 256];   // 2 x 32 KB f32, swizzled 16B units
    __shared__ float s_part[8][TM];
    __shared__ __align__(16) float s_fin[TM];
    __shared__ float acc_hi[HID];
    __shared__ float l_hi;

    const int tid  = threadIdx.x;
    const int wid  = tid >> 6;        // 0..7
    const int lane = tid & 63;
    const int l15  = lane & 15;
    const int lg   = lane >> 4;       // 0..3
    const int s7   = l15 & 7;
    const int seg  = blockIdx.x;

    // segment bounds (batch sorted ascending)
    int lo = 0, hi = N;
    while (lo < hi) { int mid = (lo + hi) >> 1; if (batch[mid] <  seg) lo = mid + 1; else hi = mid; }
    const int start = lo;
    hi = N;
    while (lo < hi) { int mid = (lo + hi) >> 1; if (batch[mid] <= seg) lo = mid + 1; else hi = mid; }
    const int end = lo;

    // ---- W1 B-frags: wave owns cols [wid*16, wid*16+16) -> 32 VGPR ----
    const int col = wid * 16 + l15;
    bf16x8 bfrag[8];
    #pragma unroll
    for (int kt = 0; kt < 8; ++kt) {
        bf16x8 b;
        #pragma unroll
        for (int j = 0; j < 8; ++j) b[j] = (__bf16)W1[(kt * 32 + lg * 8 + j) * H2 + col];
        bfrag[kt] = b;
    }
    const float b1v = b1[col];
    const float w2v = W2[col];

    const int cnt    = end - start;
    const int ntiles = (cnt + TM - 1) / TM;
    const int last   = (end > start) ? end - 1 : start;

    // staging: wave handles tile-rows {wid, 8+wid, 16+wid, 24+wid}; lane loads
    // global unit (lane ^ wid) into linear LDS slot lane  (both-sides swizzle)
    const float* gcol = x + ((lane ^ wid) << 2);

    if (ntiles > 0) {
        #pragma unroll
        for (int i = 0; i < 4; ++i) {
            const int ri = i * 8 + wid;
            int gr = start + ri; if (gr > last) gr = last;
            gload16(gcol + (size_t)gr * HID, &xs[0][ri * 256]);
        }
    }
    BAR_ALL();   // tile 0 resident

    float m_run = -INFINITY, l_run = 0.f, acc_d = 0.f;
    const int d     = tid & (HID - 1);
    const int du    = d >> 2;            // 16B unit of this dim
    const int dl4   = (d & 3) * 4;       // byte within unit
    const int row_h = (tid >> 8) * 16;   // 0 or 16: this thread's row half
    const int vA    = ((lg * 2)     ^ s7) * 16;   // swizzled A-frag byte offsets
    const int vB    = ((lg * 2 + 1) ^ s7) * 16;

    for (int t = 0; t < ntiles; ++t) {
        const int  cur      = t & 1;
        const int  row0     = start + t * TM;
        const bool has_next = (t + 1) < ntiles;

        // issue next tile's async loads NOW; they drain only at tile boundary
        if (has_next) {
            #pragma unroll
            for (int i = 0; i < 4; ++i) {
                const int ri = i * 8 + wid;
                int gr = row0 + TM + ri; if (gr > last) gr = last;
                gload16(gcol + (size_t)gr * HID, &xs[cur ^ 1][ri * 256]);
            }
        }

        // ---- h = x_tile @ W1 (bf16 MFMA, pack at read) ----
        const char* arow = (const char*)&xs[cur][0] + l15 * 1024;
        f32x4 acc0 = {0.f, 0.f, 0.f, 0.f}, acc1 = {0.f, 0.f, 0.f, 0.f};
        #pragma unroll
        for (int kt = 0; kt < 8; ++kt) {
            const char* p = arow + kt * 128;
            bf16x8 a0 = pack8(*(const f32x4*)(p + vA),
                              *(const f32x4*)(p + vB));             // rows 0..15
            bf16x8 a1 = pack8(*(const f32x4*)(p + 16384 + vA),
                              *(const f32x4*)(p + 16384 + vB));     // rows 16..31
            acc0 = __builtin_amdgcn_mfma_f32_16x16x32_bf16(a0, bfrag[kt], acc0, 0, 0, 0);
            acc1 = __builtin_amdgcn_mfma_f32_16x16x32_bf16(a1, bfrag[kt], acc1, 0, 0, 0);
        }

        // ---- partial scores: p = tanh(h + b1) * W2, reduced over 16 cols ----
        // C/D layout: col = l15, row-in-16 = lg*4 + r
        #pragma unroll
        for (int mt = 0; mt < 2; ++mt) {
            #pragma unroll
            for (int r = 0; r < 4; ++r) {
                float h  = (mt ? acc1[r] : acc0[r]) + b1v;
                float e2 = __expf(fminf(2.f * h, 80.f));
                float th = __fdividef(e2 - 1.f, e2 + 1.f);
                float p  = th * w2v;
                p += __shfl_xor(p, 1);
                p += __shfl_xor(p, 2);
                p += __shfl_xor(p, 4);
                p += __shfl_xor(p, 8);
                if (l15 == 0) s_part[wid][mt * 16 + lg * 4 + r] = p;
            }
        }
        BAR_LGKM();                      // s_part visible; async loads NOT drained
        if (tid < TM) {
            float s = s_part[0][tid];
            #pragma unroll
            for (int w = 1; w < 8; ++w) s += s_part[w][tid];
            if (row0 + tid >= end) s = -1e30f;   // mask tail rows
            s_fin[tid] = s;
        }
        BAR_LGKM();                      // s_fin visible

        // ---- online softmax + weighted accumulation (thread owns dim d) ----
        float tmax = -1e30f;
        #pragma unroll
        for (int i = 0; i < 8; ++i) {
            f32x4 v = *(const f32x4*)&s_fin[i * 4];
            tmax = fmaxf(tmax, fmaxf(fmaxf(v[0], v[1]), fmaxf(v[2], v[3])));
        }
        const float m_new = fmaxf(m_run, tmax);
        const float scale = __expf(m_run - m_new);   // first tile: exp(-inf)=0
        acc_d *= scale;
        l_run *= scale;

        const char* xbb = (const char*)&xs[cur][0];
        #pragma unroll
        for (int q = 0; q < 4; ++q) {
            f32x4 sv = *(const f32x4*)&s_fin[row_h + q * 4];   // LDS broadcast
            #pragma unroll
            for (int j = 0; j < 4; ++j) {
                const int rr  = q * 4 + j;                     // R&7 == rr&7
                const float e = __expf(sv[j] - m_new);         // masked rows -> 0
                l_run += e;
                const float xv = *(const float*)(xbb + (row_h + rr) * 1024
                                                 + ((du ^ (rr & 7)) << 4) + dl4);
                acc_d = fmaf(e, xv, acc_d);
            }
        }
        m_run = m_new;

        BAR_ALL();   // drain next tile's loads; all reads of xs[cur] complete
    }

    // combine the two row-halves; empty segment -> 0/(0+1e-8) = 0
    if (tid >= HID) {
        acc_hi[d] = acc_d;
        if (tid == HID) l_hi = l_run;
    }
    BAR_LGKM();
    if (tid < HID) {
        out[seg * HID + tid] = (acc_d + acc_hi[tid]) / (l_run + l_hi + 1e-8f);
    }
}

extern "C" void kernel_launch(void* const* d_in, const int* in_sizes, int n_in,
                              void* d_out, int out_size, void* d_ws, size_t ws_size,
                              hipStream_t stream) {
    const float* x     = (const float*)d_in[0];
    const int*   batch = (const int*)d_in[1];
    const float* W1    = (const float*)d_in[2];
    const float* b1    = (const float*)d_in[3];
    const float* W2    = (const float*)d_in[4];
    // d_in[5] = b2: uniform shift, cancels in the segment softmax — unused.
    float* out = (float*)d_out;
    const int N = in_sizes[1];

    attn_pool_kernel<<<NSEG, BLOCK, 0, stream>>>(x, batch, W1, b1, W2, out, N);
}